// Round 5
// baseline (323.480 us; speedup 1.0000x reference)
//
#include <hip/hip_runtime.h>
#include <hip/hip_bf16.h>

#define BIGV 1.0e9f

static constexpr int B_ = 32;
static constexpr int L_ = 1024;
static constexpr int F_ = 128;
static constexpr int S_ = 4;               // lane stagger (skew factor)
static constexpr int SKEW_U = 1296;        // skewed rows; producer writes <=1275, loader reads <=1279
static constexpr size_t SKEW_PB = (size_t)SKEW_U * 1024;  // floats per batch
static constexpr size_t OFF_N1 = (size_t)B_ * SKEW_PB;
static constexpr size_t OFF_N2 = OFF_N1 + (size_t)B_ * L_;
static constexpr int NSEG_ = 80;           // 80 segments x 16 steps = 1280 >= 1276

typedef __attribute__((ext_vector_type(8))) short short8;
typedef __attribute__((ext_vector_type(4))) float f32x4;

__device__ __forceinline__ unsigned pack2(float x, float y) {
  union { float f; unsigned u; } a, b;
  a.f = x; b.f = y;
  unsigned lo = (a.u + 0x7FFFu + ((a.u >> 16) & 1u)) >> 16;
  unsigned hi = (b.u + 0x7FFFu + ((b.u >> 16) & 1u)) >> 16;
  return lo | (hi << 16);
}

// one wave per row of 128 floats; ws[OFF_N1 + wid] = sum of squares
__global__ void norm_kernel(const float* __restrict__ s1, const float* __restrict__ s2,
                            float* __restrict__ ws) {
  int gt   = blockIdx.x * blockDim.x + threadIdx.x;
  int wid  = gt >> 6;
  int lane = gt & 63;
  const float* src = (wid < B_ * L_) ? (s1 + (size_t)wid * F_)
                                     : (s2 + (size_t)(wid - B_ * L_) * F_);
  float2 v = ((const float2*)src)[lane];
  float s = v.x * v.x + v.y * v.y;
#pragma unroll
  for (int o = 32; o > 0; o >>= 1) s += __shfl_xor(s, o, 64);
  if (lane == 0) ws[OFF_N1 + wid] = s;
}

// cost matrix, skewed layout: C(c, r) at (c + 4*(r>>4))*1024 + r per batch.
__global__ __launch_bounds__(256) void cost_kernel(const float* __restrict__ s1,
                                                   const float* __restrict__ s2,
                                                   float* __restrict__ ws) {
  __shared__ short aL[128][136];
  __shared__ short bL[128][136];
  __shared__ float q1[128], q2[128];

  const int tid = threadIdx.x;
  const int b   = blockIdx.y;
  const int tc  = blockIdx.x & 7;
  const int tr  = blockIdx.x >> 3;

  const float* Ap = s1 + (size_t)b * L_ * F_ + (size_t)tr * 128 * F_;
  const float* Bp = s2 + (size_t)b * L_ * F_ + (size_t)tc * 128 * F_;

#pragma unroll 4
  for (int it = 0; it < 16; ++it) {
    int idx = it * 1024 + tid * 4;
    int r = idx >> 7, cc = idx & 127;
    float4 va = *(const float4*)(Ap + idx);
    float4 vb = *(const float4*)(Bp + idx);
    *(uint2*)&aL[r][cc] = make_uint2(pack2(va.x, va.y), pack2(va.z, va.w));
    *(uint2*)&bL[r][cc] = make_uint2(pack2(vb.x, vb.y), pack2(vb.z, vb.w));
  }
  if (tid < 128) q1[tid] = ws[OFF_N1 + (size_t)b * L_ + tr * 128 + tid];
  else           q2[tid - 128] = ws[OFF_N2 + (size_t)b * L_ + tc * 128 + (tid - 128)];
  __syncthreads();

  const int wave = tid >> 6, lane = tid & 63, quad = lane >> 4, l16 = lane & 15;
  const int m0 = (wave >> 1) * 64, n0 = (wave & 1) * 64;

  f32x4 acc[4][4] = {};
#pragma unroll
  for (int kc = 0; kc < 4; ++kc) {
    short8 af[4], bf[4];
#pragma unroll
    for (int mi = 0; mi < 4; ++mi)
      af[mi] = *(const short8*)&aL[m0 + mi * 16 + l16][kc * 32 + quad * 8];
#pragma unroll
    for (int nj = 0; nj < 4; ++nj)
      bf[nj] = *(const short8*)&bL[n0 + nj * 16 + l16][kc * 32 + quad * 8];
#pragma unroll
    for (int mi = 0; mi < 4; ++mi)
#pragma unroll
      for (int nj = 0; nj < 4; ++nj)
        acc[mi][nj] = __builtin_amdgcn_mfma_f32_16x16x32_bf16(af[mi], bf[nj], acc[mi][nj], 0, 0, 0);
  }

  float* Cb = ws + (size_t)b * SKEW_PB;
#pragma unroll
  for (int mi = 0; mi < 4; ++mi)
#pragma unroll
    for (int nj = 0; nj < 4; ++nj) {
      int lr0 = m0 + mi * 16 + quad * 4;
      int lc  = n0 + nj * 16 + l16;
      int r0  = tr * 128 + lr0;
      int c   = tc * 128 + lc;
      float4 v;
      v.x = sqrtf(fmaxf(q1[lr0 + 0] + q2[lc] - 2.0f * acc[mi][nj][0], 0.0f));
      v.y = sqrtf(fmaxf(q1[lr0 + 1] + q2[lc] - 2.0f * acc[mi][nj][1], 0.0f));
      v.z = sqrtf(fmaxf(q1[lr0 + 2] + q2[lc] - 2.0f * acc[mi][nj][2], 0.0f));
      v.w = sqrtf(fmaxf(q1[lr0 + 3] + q2[lc] - 2.0f * acc[mi][nj][3], 0.0f));
      *(float4*)&Cb[(size_t)(c + S_ * (r0 >> 4)) * 1024 + r0] = v;
    }
}

// One block per batch. Wave 0 computes DTW (lane l owns rows 16l..16l+15);
// waves 1..4 stage skewed rows global->LDS one 16-row segment ahead.
// LDS rows are XOR-swizzled in float4 units (phys = j ^ ((j>>3)&7)) so both the
// loader's (q*64+lane) writes and the compute wave's (lane*4+q) reads hit each
// 4-bank group with exactly 8 lanes -> conflict-free minimum.
__global__ __launch_bounds__(320, 1) void dtw_kernel(const float* __restrict__ ws,
                                                     float* __restrict__ out) {
  __shared__ float colLds[32][1024];  // 128 KB: double-buffered 16-row segments

  const int b    = blockIdx.x;
  const int tid  = threadIdx.x;
  const int wave = tid >> 6;
  const int lane = tid & 63;
  const float* Cb = ws + (size_t)b * SKEW_PB;

  if (wave != 0) {
    // ---------------- loader waves ----------------
    const int rbase = (wave - 1) * 4;  // 4 rows per wave per segment
    const int swzW = lane >> 3;        // loader-side swizzle term
    auto loadSeg = [&](int g) {
#pragma unroll
      for (int i = 0; i < 4; ++i) {
        int u = g * 16 + rbase + i;
        const float4* src = (const float4*)(Cb + (size_t)u * 1024);
        float4* dst = (float4*)&colLds[u & 31][0];
#pragma unroll
        for (int q = 0; q < 4; ++q)
          dst[(q * 64 + lane) ^ swzW] = src[q * 64 + lane];
      }
    };
    loadSeg(0);
    for (int s = 0; s < NSEG_; ++s) {
      __syncthreads();                 // publish seg s; compute starts it
      if (s < NSEG_ - 1) loadSeg(s + 1);
    }
    return;
  }

  // ---------------- compute wave ----------------
  const int swzC = (lane >> 1) & 7;    // compute-side swizzle term
  auto ldRow = [&](int u, float4* dv) {
    const float4* base = (const float4*)&colLds[u & 31][0];
#pragma unroll
    for (int q = 0; q < 4; ++q) dv[q] = base[(lane * 4 + q) ^ swzC];
  };

  float left[16];
#pragma unroll
  for (int r = 0; r < 16; ++r) left[r] = BIGV;
  float bot = BIGV;
  float sh[4] = {BIGV, BIGV, BIGV, BIGV};
  float result = 0.0f;
  const bool l0 = (lane == 0);
  int col = -S_ * lane;  // column index at current step
  float4 pre[2][4];

  for (int s = 0; s < NSEG_; ++s) {
    __syncthreads();  // seg s ready in LDS half (s&1)
    ldRow(16 * s, pre[0]);
    ldRow(16 * s + 1, pre[1]);
#pragma unroll
    for (int k = 0; k < 16; ++k) {
      const int t = 16 * s + k;
      float shN = __shfl_up(bot, 1, 64);

      const float4* cb = pre[k & 1];
      float cv[16] = { cb[0].x, cb[0].y, cb[0].z, cb[0].w,
                       cb[1].x, cb[1].y, cb[1].z, cb[1].w,
                       cb[2].x, cb[2].y, cb[2].z, cb[2].w,
                       cb[3].x, cb[3].y, cb[3].z, cb[3].w };

      if (k < 14) {  // depth-2 LDS prefetch (stays within seg s)
        ldRow(t + 2, pre[k & 1]);
      }

      // ring: slot written at t read as diag at t+4, as up at t+3
      float dgT = l0 ? ((t == 0) ? 0.0f : BIGV) : sh[k & 3];
      float upT = l0 ? BIGV : sh[(k + 1) & 3];
      bool act = ((unsigned)col < 1024u);
      float c0 = act ? cv[0] : BIGV;  // only head masked; induction keeps
                                      // inactive-lane state >= ~1e9
      float cur = c0 + fminf(fminf(dgT, upT), left[0]);
      float nl[16];
      nl[0] = cur;
#pragma unroll
      for (int r = 1; r < 16; ++r) {
        cur = cv[r] + fminf(fminf(left[r - 1], left[r]), cur);  // v_min3 + v_add
        nl[r] = cur;
      }
#pragma unroll
      for (int r = 0; r < 16; ++r) left[r] = nl[r];
      bot = nl[15];
      sh[k & 3] = shN;

      if (t == 1275) result = bot;  // lane 63 at c=1023: D[1024][1024]
      col += 1;
    }
  }
  if (lane == 63) out[b] = 1.0f / (1.0f + result * (1.0f / 2048.0f));
}

extern "C" void kernel_launch(void* const* d_in, const int* in_sizes, int n_in,
                              void* d_out, int out_size, void* d_ws, size_t ws_size,
                              hipStream_t stream) {
  const float* s1 = (const float*)d_in[0];
  const float* s2 = (const float*)d_in[1];
  float* out = (float*)d_out;
  float* ws  = (float*)d_ws;

  norm_kernel<<<dim3((2 * B_ * L_) / 4), 256, 0, stream>>>(s1, s2, ws);
  cost_kernel<<<dim3(64, B_), 256, 0, stream>>>(s1, s2, ws);
  dtw_kernel<<<dim3(B_), 320, 0, stream>>>(ws, out);
}

// Round 6
// 320.499 us; speedup vs baseline: 1.0093x; 1.0093x over previous
//
#include <hip/hip_runtime.h>
#include <hip/hip_bf16.h>

#define BIGV 1.0e9f

static constexpr int B_ = 32;
static constexpr int L_ = 1024;
static constexpr int F_ = 128;
static constexpr int S_ = 4;          // in-wave lane stagger (columns)
static constexpr int UDIM_ = 1280;    // skewed u-rows per stream (max used 1275)
static constexpr int LAG_ = 288;      // wave1 global-step lag (18 segments)
static constexpr int NSEGL_ = 80;     // local segments per wave (1280 steps)
static constexpr int NSEGG_ = 98;     // global segments (1568 steps)
static constexpr size_t STREAM_US = (size_t)B_ * 2 * UDIM_ * 512;  // ushorts

typedef __attribute__((ext_vector_type(8))) short short8;
typedef __attribute__((ext_vector_type(4))) float f32x4;

__device__ __forceinline__ unsigned pack2(float x, float y) {
  union { float f; unsigned u; } a, b;
  a.f = x; b.f = y;
  unsigned lo = (a.u + 0x7FFFu + ((a.u >> 16) & 1u)) >> 16;
  unsigned hi = (b.u + 0x7FFFu + ((b.u >> 16) & 1u)) >> 16;
  return lo | (hi << 16);
}

// one wave per row of 128 floats; nrm[wid] = sum of squares
__global__ void norm_kernel(const float* __restrict__ s1, const float* __restrict__ s2,
                            float* __restrict__ nrm) {
  int gt   = blockIdx.x * blockDim.x + threadIdx.x;
  int wid  = gt >> 6;
  int lane = gt & 63;
  const float* src = (wid < B_ * L_) ? (s1 + (size_t)wid * F_)
                                     : (s2 + (size_t)(wid - B_ * L_) * F_);
  float2 v = ((const float2*)src)[lane];
  float s = v.x * v.x + v.y * v.y;
#pragma unroll
  for (int o = 32; o > 0; o >>= 1) s += __shfl_xor(s, o, 64);
  if (lane == 0) nrm[wid] = s;
}

// cost matrix -> bf16, two skewed streams per batch (one per dtw compute wave):
// global row r: w = r>>9, rl = r&511; element (r, col c) stored at
// stream[(b*2+w)][u = c + 4*(rl>>3)][rl].
__global__ __launch_bounds__(256) void cost_kernel(const float* __restrict__ s1,
                                                   const float* __restrict__ s2,
                                                   ushort* __restrict__ stream,
                                                   const float* __restrict__ nrm) {
  __shared__ short aL[128][136];
  __shared__ short bL[128][136];
  __shared__ float q1[128], q2[128];

  const int tid = threadIdx.x;
  const int b   = blockIdx.y;
  const int tc  = blockIdx.x & 7;
  const int tr  = blockIdx.x >> 3;

  const float* Ap = s1 + (size_t)b * L_ * F_ + (size_t)tr * 128 * F_;
  const float* Bp = s2 + (size_t)b * L_ * F_ + (size_t)tc * 128 * F_;

#pragma unroll 4
  for (int it = 0; it < 16; ++it) {
    int idx = it * 1024 + tid * 4;
    int r = idx >> 7, cc = idx & 127;
    float4 va = *(const float4*)(Ap + idx);
    float4 vb = *(const float4*)(Bp + idx);
    *(uint2*)&aL[r][cc] = make_uint2(pack2(va.x, va.y), pack2(va.z, va.w));
    *(uint2*)&bL[r][cc] = make_uint2(pack2(vb.x, vb.y), pack2(vb.z, vb.w));
  }
  if (tid < 128) q1[tid] = nrm[(size_t)b * L_ + tr * 128 + tid];
  else           q2[tid - 128] = nrm[(size_t)B_ * L_ + (size_t)b * L_ + tc * 128 + (tid - 128)];
  __syncthreads();

  const int wave = tid >> 6, lane = tid & 63, quad = lane >> 4, l16 = lane & 15;
  const int m0 = (wave >> 1) * 64, n0 = (wave & 1) * 64;

  f32x4 acc[4][4] = {};
#pragma unroll
  for (int kc = 0; kc < 4; ++kc) {
    short8 af[4], bf[4];
#pragma unroll
    for (int mi = 0; mi < 4; ++mi)
      af[mi] = *(const short8*)&aL[m0 + mi * 16 + l16][kc * 32 + quad * 8];
#pragma unroll
    for (int nj = 0; nj < 4; ++nj)
      bf[nj] = *(const short8*)&bL[n0 + nj * 16 + l16][kc * 32 + quad * 8];
#pragma unroll
    for (int mi = 0; mi < 4; ++mi)
#pragma unroll
      for (int nj = 0; nj < 4; ++nj)
        acc[mi][nj] = __builtin_amdgcn_mfma_f32_16x16x32_bf16(af[mi], bf[nj], acc[mi][nj], 0, 0, 0);
  }

  ushort* Sb = stream + (size_t)(b * 2) * UDIM_ * 512;
#pragma unroll
  for (int mi = 0; mi < 4; ++mi)
#pragma unroll
    for (int nj = 0; nj < 4; ++nj) {
      int lr0 = m0 + mi * 16 + quad * 4;
      int lc  = n0 + nj * 16 + l16;
      int r0  = tr * 128 + lr0;   // 4-aligned: rows r0..r0+3 share (rl>>3)
      int c   = tc * 128 + lc;
      float vx = sqrtf(fmaxf(q1[lr0 + 0] + q2[lc] - 2.0f * acc[mi][nj][0], 0.0f));
      float vy = sqrtf(fmaxf(q1[lr0 + 1] + q2[lc] - 2.0f * acc[mi][nj][1], 0.0f));
      float vz = sqrtf(fmaxf(q1[lr0 + 2] + q2[lc] - 2.0f * acc[mi][nj][2], 0.0f));
      float vw = sqrtf(fmaxf(q1[lr0 + 3] + q2[lc] - 2.0f * acc[mi][nj][3], 0.0f));
      int w  = r0 >> 9;
      int rl = r0 & 511;
      int u  = c + 4 * (rl >> 3);
      ushort* p = Sb + ((size_t)w * UDIM_ + u) * 512 + rl;
      *(uint2*)p = make_uint2(pack2(vx, vy), pack2(vz, vw));
    }
}

// One block per batch, 4 waves:
//   wave0: DTW rows 0..511   (8 rows/lane), local steps 0..1279
//   wave1: DTW rows 512..1023, lagging LAG_ global steps; row-511 handoff via hand[]
//   wave2/3: loaders staging stream0/stream1 u-rows into double-buffered LDS segs
__global__ __launch_bounds__(256, 1) void dtw_kernel(const ushort* __restrict__ stream,
                                                     float* __restrict__ out) {
  __shared__ ushort ldsA[2][16][512];  // 32 KB, wave0 stream
  __shared__ ushort ldsB[2][16][512];  // 32 KB, wave1 stream
  __shared__ float hand[1024];         // row-511 D values by column

  const int b    = blockIdx.x;
  const int tid  = threadIdx.x;
  const int wave = tid >> 6;
  const int lane = tid & 63;

  if (wave >= 2) {
    // ---------------- loader waves ----------------
    const int ls = wave - 2;  // 0 -> stream A, 1 -> stream B
    const ushort* src = stream + (size_t)(b * 2 + ls) * UDIM_ * 512;
    auto loadSeg = [&](int g, int buf) {
      ushort(*dst)[512] = ls ? ldsB[buf] : ldsA[buf];
#pragma unroll
      for (int i = 0; i < 16; ++i) {
        const uint4* sp = (const uint4*)(src + (size_t)(g * 16 + i) * 512);
        *(uint4*)&dst[i][lane * 8] = sp[lane];
      }
    };
    if (ls == 0) loadSeg(0, 0);  // preload wave0 seg 0
    for (int n = 0; n < NSEGG_; ++n) {
      __syncthreads();
      int g = (ls == 0) ? (n + 1) : (n - 17);  // B's local seg m+1 = n-17
      if ((unsigned)g < (unsigned)NSEGL_) loadSeg(g, g & 1);
    }
    return;
  }

  // ---------------- compute waves ----------------
  const int w = wave;  // 0 or 1
  const bool l0 = (lane == 0);

  float left[8];
#pragma unroll
  for (int r = 0; r < 8; ++r) left[r] = BIGV;
  float bot = BIGV;
  float sh[4] = {BIGV, BIGV, BIGV, BIGV};
  float hPrev = BIGV, result = 0.0f;
  uint4 pre[2];

  for (int n = 0; n < NSEGG_; ++n) {
    __syncthreads();  // publishes loader seg + hand writes from >=2 phases ago
    const int sBase = 16 * n - (w ? LAG_ : 0);  // local step of k=0
    if ((unsigned)sBase >= 1280u) continue;     // idle phase (barrier already hit)

    const int buf = (sBase >> 4) & 1;
    const ushort(*lds)[512] = w ? ldsB[buf] : ldsA[buf];
    pre[0] = *(const uint4*)&lds[0][lane * 8];
    pre[1] = *(const uint4*)&lds[1][lane * 8];

#pragma unroll
    for (int k = 0; k < 16; ++k) {
      const int s = sBase + k;          // local step
      const int col = s - S_ * lane;    // this lane's column
      float shN = __shfl_up(bot, 1, 64);
      float hCur = hand[s & 1023];      // wave-uniform broadcast read

      uint4 cw = pre[k & 1];
      if (k < 14) pre[k & 1] = *(const uint4*)&lds[k + 2][lane * 8];

      float cv[8];
      cv[0] = __uint_as_float(cw.x << 16);
      cv[1] = __uint_as_float(cw.x & 0xFFFF0000u);
      cv[2] = __uint_as_float(cw.y << 16);
      cv[3] = __uint_as_float(cw.y & 0xFFFF0000u);
      cv[4] = __uint_as_float(cw.z << 16);
      cv[5] = __uint_as_float(cw.z & 0xFFFF0000u);
      cv[6] = __uint_as_float(cw.w << 16);
      cv[7] = __uint_as_float(cw.w & 0xFFFF0000u);

      // ring: slot written at step t is read as diag at t+4, as up at t+3
      float dgT = sh[k & 3];
      float upT = sh[(k + 1) & 3];
      if (l0) {
        if (w == 0) { dgT = (s == 0) ? 0.0f : BIGV; upT = BIGV; }
        else        { dgT = (s == 0) ? BIGV : hPrev; upT = hCur; }
      }
      bool act = ((unsigned)col < 1024u);
      float c0 = act ? cv[0] : BIGV;  // head-only mask; induction keeps
                                      // inactive-lane state >= ~1e9
      float cur = c0 + fminf(fminf(dgT, upT), left[0]);
      float nl[8];
      nl[0] = cur;
#pragma unroll
      for (int r = 1; r < 8; ++r) {
        cur = cv[r] + fminf(fminf(left[r - 1], left[r]), cur);  // v_min3 + v_add
        nl[r] = cur;
      }
#pragma unroll
      for (int r = 0; r < 8; ++r) left[r] = nl[r];
      bot = nl[7];
      sh[k & 3] = shN;
      hPrev = hCur;

      if (w == 0) {
        int j = s - 252;  // lane63's column this step
        if (lane == 63 && (unsigned)j < 1024u) hand[j] = bot;
      } else if (s == 1275) {
        result = bot;  // lane63 at col 1023: D[1024][1024]
      }
    }
  }
  if (w == 1 && lane == 63) out[b] = 1.0f / (1.0f + result * (1.0f / 2048.0f));
}

extern "C" void kernel_launch(void* const* d_in, const int* in_sizes, int n_in,
                              void* d_out, int out_size, void* d_ws, size_t ws_size,
                              hipStream_t stream_) {
  const float* s1 = (const float*)d_in[0];
  const float* s2 = (const float*)d_in[1];
  float* out = (float*)d_out;
  ushort* cws = (ushort*)d_ws;
  float* nrm = (float*)(cws + STREAM_US);

  norm_kernel<<<dim3((2 * B_ * L_) / 4), 256, 0, stream_>>>(s1, s2, nrm);
  cost_kernel<<<dim3(64, B_), 256, 0, stream_>>>(s1, s2, cws, nrm);
  dtw_kernel<<<dim3(B_), 256, 0, stream_>>>(cws, out);
}

// Round 7
// 254.063 us; speedup vs baseline: 1.2732x; 1.2615x over previous
//
#include <hip/hip_runtime.h>
#include <hip/hip_bf16.h>

#define BIGV 1.0e9f

static constexpr int B_ = 32;
static constexpr int L_ = 1024;
static constexpr int F_ = 128;
static constexpr int S_ = 4;          // in-wave lane stagger (columns)
static constexpr int UDIM_ = 1280;    // skewed u-rows per stream (max used 1275)
static constexpr int LAG_ = 288;      // wave1 global-step lag (18 segments)
static constexpr int NSEGL_ = 80;     // local segments per wave (1280 steps)
static constexpr int NSEGG_ = 98;     // global segments (1568 steps)
static constexpr size_t STREAM_US = (size_t)B_ * 2 * UDIM_ * 512;  // ushorts

typedef __attribute__((ext_vector_type(8))) short short8;
typedef __attribute__((ext_vector_type(4))) float f32x4;

__device__ __forceinline__ unsigned pack2(float x, float y) {
  union { float f; unsigned u; } a, b;
  a.f = x; b.f = y;
  unsigned lo = (a.u + 0x7FFFu + ((a.u >> 16) & 1u)) >> 16;
  unsigned hi = (b.u + 0x7FFFu + ((b.u >> 16) & 1u)) >> 16;
  return lo | (hi << 16);
}

// one wave per row of 128 floats; nrm[wid] = sum of squares
__global__ void norm_kernel(const float* __restrict__ s1, const float* __restrict__ s2,
                            float* __restrict__ nrm) {
  int gt   = blockIdx.x * blockDim.x + threadIdx.x;
  int wid  = gt >> 6;
  int lane = gt & 63;
  const float* src = (wid < B_ * L_) ? (s1 + (size_t)wid * F_)
                                     : (s2 + (size_t)(wid - B_ * L_) * F_);
  float2 v = ((const float2*)src)[lane];
  float s = v.x * v.x + v.y * v.y;
#pragma unroll
  for (int o = 32; o > 0; o >>= 1) s += __shfl_xor(s, o, 64);
  if (lane == 0) nrm[wid] = s;
}

// cost matrix -> bf16, two skewed streams per batch (one per dtw compute wave):
// global row r: w = r>>9, rl = r&511; element (r, col c) stored at
// stream[(b*2+w)][u = c + 4*(rl>>3)][rl].
__global__ __launch_bounds__(256) void cost_kernel(const float* __restrict__ s1,
                                                   const float* __restrict__ s2,
                                                   ushort* __restrict__ stream,
                                                   const float* __restrict__ nrm) {
  __shared__ short aL[128][136];
  __shared__ short bL[128][136];
  __shared__ float q1[128], q2[128];

  const int tid = threadIdx.x;
  const int b   = blockIdx.y;
  const int tc  = blockIdx.x & 7;
  const int tr  = blockIdx.x >> 3;

  const float* Ap = s1 + (size_t)b * L_ * F_ + (size_t)tr * 128 * F_;
  const float* Bp = s2 + (size_t)b * L_ * F_ + (size_t)tc * 128 * F_;

#pragma unroll 4
  for (int it = 0; it < 16; ++it) {
    int idx = it * 1024 + tid * 4;
    int r = idx >> 7, cc = idx & 127;
    float4 va = *(const float4*)(Ap + idx);
    float4 vb = *(const float4*)(Bp + idx);
    *(uint2*)&aL[r][cc] = make_uint2(pack2(va.x, va.y), pack2(va.z, va.w));
    *(uint2*)&bL[r][cc] = make_uint2(pack2(vb.x, vb.y), pack2(vb.z, vb.w));
  }
  if (tid < 128) q1[tid] = nrm[(size_t)b * L_ + tr * 128 + tid];
  else           q2[tid - 128] = nrm[(size_t)B_ * L_ + (size_t)b * L_ + tc * 128 + (tid - 128)];
  __syncthreads();

  const int wave = tid >> 6, lane = tid & 63, quad = lane >> 4, l16 = lane & 15;
  const int m0 = (wave >> 1) * 64, n0 = (wave & 1) * 64;

  f32x4 acc[4][4] = {};
#pragma unroll
  for (int kc = 0; kc < 4; ++kc) {
    short8 af[4], bf[4];
#pragma unroll
    for (int mi = 0; mi < 4; ++mi)
      af[mi] = *(const short8*)&aL[m0 + mi * 16 + l16][kc * 32 + quad * 8];
#pragma unroll
    for (int nj = 0; nj < 4; ++nj)
      bf[nj] = *(const short8*)&bL[n0 + nj * 16 + l16][kc * 32 + quad * 8];
#pragma unroll
    for (int mi = 0; mi < 4; ++mi)
#pragma unroll
      for (int nj = 0; nj < 4; ++nj)
        acc[mi][nj] = __builtin_amdgcn_mfma_f32_16x16x32_bf16(af[mi], bf[nj], acc[mi][nj], 0, 0, 0);
  }

  ushort* Sb = stream + (size_t)(b * 2) * UDIM_ * 512;
#pragma unroll
  for (int mi = 0; mi < 4; ++mi)
#pragma unroll
    for (int nj = 0; nj < 4; ++nj) {
      int lr0 = m0 + mi * 16 + quad * 4;
      int lc  = n0 + nj * 16 + l16;
      int r0  = tr * 128 + lr0;   // 4-aligned: rows r0..r0+3 share (rl>>3)
      int c   = tc * 128 + lc;
      float vx = sqrtf(fmaxf(q1[lr0 + 0] + q2[lc] - 2.0f * acc[mi][nj][0], 0.0f));
      float vy = sqrtf(fmaxf(q1[lr0 + 1] + q2[lc] - 2.0f * acc[mi][nj][1], 0.0f));
      float vz = sqrtf(fmaxf(q1[lr0 + 2] + q2[lc] - 2.0f * acc[mi][nj][2], 0.0f));
      float vw = sqrtf(fmaxf(q1[lr0 + 3] + q2[lc] - 2.0f * acc[mi][nj][3], 0.0f));
      int w  = r0 >> 9;
      int rl = r0 & 511;
      int u  = c + 4 * (rl >> 3);
      ushort* p = Sb + ((size_t)w * UDIM_ + u) * 512 + rl;
      *(uint2*)p = make_uint2(pack2(vx, vy), pack2(vz, vw));
    }
}

// One block per batch, 4 waves:
//   wave0: DTW rows 0..511   (8 rows/lane), local steps 0..1279; writes hand[]
//   wave1: DTW rows 512..1023, lagging LAG_; reads hand[] via 4-deep register
//          ring (prefetch 4 steps ahead -> LDS latency off the serial chain)
//   wave2/3: loaders staging stream0/stream1 u-rows into double-buffered LDS segs
__global__ __launch_bounds__(256, 1) void dtw_kernel(const ushort* __restrict__ stream,
                                                     float* __restrict__ out) {
  __shared__ ushort ldsA[2][16][512];  // 32 KB, wave0 stream
  __shared__ ushort ldsB[2][16][512];  // 32 KB, wave1 stream
  __shared__ float hand[1024];         // row-511 D values by column

  const int b    = blockIdx.x;
  const int tid  = threadIdx.x;
  const int wave = tid >> 6;
  const int lane = tid & 63;

  if (wave >= 2) {
    // ---------------- loader waves ----------------
    const int ls = wave - 2;  // 0 -> stream A, 1 -> stream B
    const ushort* src = stream + (size_t)(b * 2 + ls) * UDIM_ * 512;
    auto loadSeg = [&](int g, int buf) {
      ushort(*dst)[512] = ls ? ldsB[buf] : ldsA[buf];
#pragma unroll
      for (int i = 0; i < 16; ++i) {
        const uint4* sp = (const uint4*)(src + (size_t)(g * 16 + i) * 512);
        *(uint4*)&dst[i][lane * 8] = sp[lane];
      }
    };
    if (ls == 0) loadSeg(0, 0);  // preload wave0 seg 0
    for (int n = 0; n < NSEGG_; ++n) {
      __syncthreads();
      int g = (ls == 0) ? (n + 1) : (n - 17);  // B's local seg m+1 = n-17
      if ((unsigned)g < (unsigned)NSEGL_) loadSeg(g, g & 1);
    }
    return;
  }

  // ---------------- compute waves ----------------
  const bool l0 = (lane == 0);
  float left[8];
#pragma unroll
  for (int r = 0; r < 8; ++r) left[r] = BIGV;
  float bot = BIGV;
  float sh[4] = {BIGV, BIGV, BIGV, BIGV};
  uint4 pre[2];

  if (wave == 0) {
    // ---- rows 0..511; no hand reads ----
    for (int n = 0; n < NSEGG_; ++n) {
      __syncthreads();
      const int sBase = 16 * n;
      if (sBase >= 1280) continue;
      const ushort(*lds)[512] = ldsA[n & 1];
      pre[0] = *(const uint4*)&lds[0][lane * 8];
      pre[1] = *(const uint4*)&lds[1][lane * 8];
#pragma unroll
      for (int k = 0; k < 16; ++k) {
        const int s = sBase + k;
        const int col = s - S_ * lane;
        float shN = __shfl_up(bot, 1, 64);
        uint4 cw = pre[k & 1];
        if (k < 14) pre[k & 1] = *(const uint4*)&lds[k + 2][lane * 8];

        float cv[8];
        cv[0] = __uint_as_float(cw.x << 16);
        cv[1] = __uint_as_float(cw.x & 0xFFFF0000u);
        cv[2] = __uint_as_float(cw.y << 16);
        cv[3] = __uint_as_float(cw.y & 0xFFFF0000u);
        cv[4] = __uint_as_float(cw.z << 16);
        cv[5] = __uint_as_float(cw.z & 0xFFFF0000u);
        cv[6] = __uint_as_float(cw.w << 16);
        cv[7] = __uint_as_float(cw.w & 0xFFFF0000u);

        float dgT = l0 ? ((s == 0) ? 0.0f : BIGV) : sh[k & 3];
        float upT = l0 ? BIGV : sh[(k + 1) & 3];
        bool act = ((unsigned)col < 1024u);
        float c0 = act ? cv[0] : BIGV;
        float cur = c0 + fminf(fminf(dgT, upT), left[0]);
        float nl[8];
        nl[0] = cur;
#pragma unroll
        for (int r = 1; r < 8; ++r) {
          cur = cv[r] + fminf(fminf(left[r - 1], left[r]), cur);
          nl[r] = cur;
        }
#pragma unroll
        for (int r = 0; r < 8; ++r) left[r] = nl[r];
        bot = nl[7];
        sh[k & 3] = shN;

        int j = s - 252;  // lane63's column this step
        if (lane == 63 && (unsigned)j < 1024u) hand[j] = bot;
      }
    }
    return;
  }

  // ---- wave 1: rows 512..1023, hand read via prefetch ring ----
  float hPrev = BIGV, result = 0.0f;
  float hRing[4];
  for (int n = 0; n < NSEGG_; ++n) {
    __syncthreads();
    const int sBase = 16 * n - LAG_;
    if ((unsigned)sBase >= 1280u) continue;
    const ushort(*lds)[512] = ldsB[(sBase >> 4) & 1];
    pre[0] = *(const uint4*)&lds[0][lane * 8];
    pre[1] = *(const uint4*)&lds[1][lane * 8];
#pragma unroll
    for (int i = 0; i < 4; ++i) hRing[i] = hand[(sBase + i) & 1023];
#pragma unroll
    for (int k = 0; k < 16; ++k) {
      const int s = sBase + k;
      const int col = s - S_ * lane;
      float shN = __shfl_up(bot, 1, 64);
      float hCur = hRing[k & 3];
      uint4 cw = pre[k & 1];
      if (k < 14) pre[k & 1] = *(const uint4*)&lds[k + 2][lane * 8];
      hRing[k & 3] = hand[(s + 4) & 1023];  // for step k+4 (slack 4 steps)

      float cv[8];
      cv[0] = __uint_as_float(cw.x << 16);
      cv[1] = __uint_as_float(cw.x & 0xFFFF0000u);
      cv[2] = __uint_as_float(cw.y << 16);
      cv[3] = __uint_as_float(cw.y & 0xFFFF0000u);
      cv[4] = __uint_as_float(cw.z << 16);
      cv[5] = __uint_as_float(cw.z & 0xFFFF0000u);
      cv[6] = __uint_as_float(cw.w << 16);
      cv[7] = __uint_as_float(cw.w & 0xFFFF0000u);

      float dgT = l0 ? ((s == 0) ? BIGV : hPrev) : sh[k & 3];
      float upT = l0 ? hCur : sh[(k + 1) & 3];
      bool act = ((unsigned)col < 1024u);
      float c0 = act ? cv[0] : BIGV;
      float cur = c0 + fminf(fminf(dgT, upT), left[0]);
      float nl[8];
      nl[0] = cur;
#pragma unroll
      for (int r = 1; r < 8; ++r) {
        cur = cv[r] + fminf(fminf(left[r - 1], left[r]), cur);
        nl[r] = cur;
      }
#pragma unroll
      for (int r = 0; r < 8; ++r) left[r] = nl[r];
      bot = nl[7];
      sh[k & 3] = shN;
      hPrev = hCur;

      if (s == 1275) result = bot;  // lane63 at col 1023: D[1024][1024]
    }
  }
  if (lane == 63) out[b] = 1.0f / (1.0f + result * (1.0f / 2048.0f));
}

extern "C" void kernel_launch(void* const* d_in, const int* in_sizes, int n_in,
                              void* d_out, int out_size, void* d_ws, size_t ws_size,
                              hipStream_t stream_) {
  const float* s1 = (const float*)d_in[0];
  const float* s2 = (const float*)d_in[1];
  float* out = (float*)d_out;
  ushort* cws = (ushort*)d_ws;
  float* nrm = (float*)(cws + STREAM_US);

  norm_kernel<<<dim3((2 * B_ * L_) / 4), 256, 0, stream_>>>(s1, s2, nrm);
  cost_kernel<<<dim3(64, B_), 256, 0, stream_>>>(s1, s2, cws, nrm);
  dtw_kernel<<<dim3(B_), 256, 0, stream_>>>(cws, out);
}